// Round 6
// baseline (36.003 us; speedup 1.0000x reference)
//
#include <hip/hip_runtime.h>

#define CC  256
#define HW  4096
#define HH  64
#define WW  64
#define RED 64
#define K2  49
#define NG  16
#define GCH 16

typedef __attribute__((ext_vector_type(8))) short bf16x8;
typedef __attribute__((ext_vector_type(4))) float f32x4;

__device__ inline unsigned short f2bf(float f) {
    union { float f; unsigned u; } v; v.f = f;
    unsigned r = v.u + 0x7FFF + ((v.u >> 16) & 1);   // round-to-nearest-even
    return (unsigned short)(r >> 16);
}

// ws layout (shorts): w1bf [64][256] at 0 (16384) ; w2bf [832][64] at 16384 (53248)
// then floats at byte 139264: sc[64], sh[64]
#define W1BF_OFF   0
#define W2BF_OFF   16384
#define W2BF_ROWS  832
#define SCSH_BYTE  139264
#define WS_NEED    (139264 + 512)

// ================= Kernel 0: precompute bf16 weights + BN fold =================
// ids 0..2047: w1 8-elt chunks; 2048..8703: w2bf 8-elt chunks (zero pad); 8704..8767: sc/sh
__global__ __launch_bounds__(256) void k0_prep(
    const float* __restrict__ w1,
    const float* __restrict__ w2,
    const float* __restrict__ gamma,
    const float* __restrict__ beta,
    const float* __restrict__ mean,
    const float* __restrict__ var,
    unsigned short* __restrict__ wsu,
    float* __restrict__ scsh)
{
    const int id = blockIdx.x * 256 + threadIdx.x;
    if (id < 2048) {                       // w1 -> bf16
        const float4 a = *reinterpret_cast<const float4*>(w1 + id * 8);
        const float4 b = *reinterpret_cast<const float4*>(w1 + id * 8 + 4);
        unsigned short r8[8] = {f2bf(a.x), f2bf(a.y), f2bf(a.z), f2bf(a.w),
                                f2bf(b.x), f2bf(b.y), f2bf(b.z), f2bf(b.w)};
        *reinterpret_cast<uint4*>(wsu + W1BF_OFF + id * 8) = *reinterpret_cast<const uint4*>(r8);
    } else if (id < 8704) {                // w2 -> bf16 (+ zero pad rows 784..831)
        const int c2 = id - 2048;
        unsigned short r8[8];
        if (c2 * 8 < K2 * NG * RED) {
            const float4 a = *reinterpret_cast<const float4*>(w2 + c2 * 8);
            const float4 b = *reinterpret_cast<const float4*>(w2 + c2 * 8 + 4);
            r8[0] = f2bf(a.x); r8[1] = f2bf(a.y); r8[2] = f2bf(a.z); r8[3] = f2bf(a.w);
            r8[4] = f2bf(b.x); r8[5] = f2bf(b.y); r8[6] = f2bf(b.z); r8[7] = f2bf(b.w);
        } else {
            #pragma unroll
            for (int i = 0; i < 8; ++i) r8[i] = 0;
        }
        *reinterpret_cast<uint4*>(wsu + W2BF_OFF + c2 * 8) = *reinterpret_cast<const uint4*>(r8);
    } else if (id < 8768) {                // BN fold
        const int o = id - 8704;
        const float sc = gamma[o] * rsqrtf(var[o] + 1e-5f);
        scsh[o]      = sc;
        scsh[o + 64] = beta[o] - mean[o] * sc;
    }
}

// ================= Fused kernel: phase A + B (MFMA) + C (involution) =================
// grid: (bb, y, gq) = 2*64*4 = 512 blocks (2/CU), 256 thr (4 waves).
// Phase A: wave wv = n-tile nt; t[:, y, :] -> st LDS (bf16, [x][r]).
// Phase B: wave wv = group gi (g = gq*4+gi); wg[4][49][68] f32 in LDS.
// Phase C: thread = (gi = tid>>6, clq = (tid>>4)&3, xq = tid&15): 4 ch x 4 px.
__global__ __launch_bounds__(256, 2) void fused_kernel(
    const float* __restrict__ feat,
    const float* __restrict__ guide,
    const unsigned short* __restrict__ wsu,
    const float* __restrict__ scsh,
    const float* __restrict__ b2,
    float* __restrict__ out)
{
    __shared__ unsigned short st[WW][80];      // t bf16, [x][r], stride 160B (16B-mult)
    __shared__ float wg[4][K2][68];            // weights, stride 272B (16B-mult)

    const int bid = blockIdx.x;
    const int bb  = bid >> 8;
    const int y   = (bid >> 2) & 63;
    const int gq  = bid & 3;
    const int tid  = threadIdx.x;
    const int lane = tid & 63;
    const int wv   = __builtin_amdgcn_readfirstlane(tid >> 6);
    const int lm = lane & 15;
    const int lg = lane >> 4;

    const unsigned short* w1bf = wsu + W1BF_OFF;
    const unsigned short* w2bf = wsu + W2BF_OFF;

    // ---------------- Phase A: t(:, y, nt*16..+15), nt = wv ----------------
    {
        const int nt = wv;
        const int px = nt * 16 + lm;
        const float* gcol = guide + (size_t)bb * CC * HW + (size_t)y * WW + px;

        f32x4 acc[4] = {f32x4{0,0,0,0}, f32x4{0,0,0,0}, f32x4{0,0,0,0}, f32x4{0,0,0,0}};
        #pragma unroll
        for (int ks = 0; ks < 8; ++ks) {
            const int cbase = ks * 32 + lg * 8;
            union { unsigned short u[8]; bf16x8 v; } B;
            #pragma unroll
            for (int j = 0; j < 8; ++j)
                B.u[j] = f2bf(gcol[(size_t)(cbase + j) * HW]);
            #pragma unroll
            for (int mt = 0; mt < 4; ++mt) {
                const bf16x8 afr = *reinterpret_cast<const bf16x8*>(
                    w1bf + (size_t)(mt * 16 + lm) * CC + cbase);
                acc[mt] = __builtin_amdgcn_mfma_f32_16x16x32_bf16(afr, B.v, acc[mt], 0, 0, 0);
            }
        }
        // epilogue: lane holds t[o = mt*16+lg*4+rr][px]; BN+ReLU -> st[px][o]
        #pragma unroll
        for (int mt = 0; mt < 4; ++mt) {
            const float4 sc4 = *reinterpret_cast<const float4*>(scsh + mt * 16 + lg * 4);
            const float4 sh4 = *reinterpret_cast<const float4*>(scsh + 64 + mt * 16 + lg * 4);
            union { unsigned short u[4]; uint2 v; } R;
            float v0 = fmaf(acc[mt][0], sc4.x, sh4.x);
            float v1 = fmaf(acc[mt][1], sc4.y, sh4.y);
            float v2 = fmaf(acc[mt][2], sc4.z, sh4.z);
            float v3 = fmaf(acc[mt][3], sc4.w, sh4.w);
            R.u[0] = f2bf(v0 > 0.f ? v0 : 0.f);
            R.u[1] = f2bf(v1 > 0.f ? v1 : 0.f);
            R.u[2] = f2bf(v2 > 0.f ? v2 : 0.f);
            R.u[3] = f2bf(v3 > 0.f ? v3 : 0.f);
            *reinterpret_cast<uint2*>(&st[px][mt * 16 + lg * 4]) = R.v;
        }
    }
    __syncthreads();

    // ---------------- Phase B: group gi = wv ----------------
    {
        const int gi    = wv;
        const int g     = gq * 4 + gi;
        const int obase = g * K2;

        f32x4 acc[4][4];    // [nt][mt]
        #pragma unroll
        for (int nt = 0; nt < 4; ++nt)
            #pragma unroll
            for (int mt = 0; mt < 4; ++mt) acc[nt][mt] = f32x4{0, 0, 0, 0};

        #pragma unroll
        for (int ks = 0; ks < 2; ++ks) {
            bf16x8 bfr[4];
            #pragma unroll
            for (int nt = 0; nt < 4; ++nt)
                bfr[nt] = *reinterpret_cast<const bf16x8*>(&st[nt * 16 + lm][ks * 32 + lg * 8]);
            #pragma unroll
            for (int mt = 0; mt < 4; ++mt) {
                const bf16x8 afr = *reinterpret_cast<const bf16x8*>(
                    w2bf + (size_t)(obase + mt * 16 + lm) * RED + ks * 32 + lg * 8);
                #pragma unroll
                for (int nt = 0; nt < 4; ++nt)
                    acc[nt][mt] = __builtin_amdgcn_mfma_f32_16x16x32_bf16(afr, bfr[nt], acc[nt][mt], 0, 0, 0);
            }
        }
        // bias (scalar, guarded: b2 has exactly 784 elts)
        float bias[4][4];
        #pragma unroll
        for (int mt = 0; mt < 4; ++mt)
            #pragma unroll
            for (int rr = 0; rr < 4; ++rr) {
                const int o2 = mt * 16 + lg * 4 + rr;
                bias[mt][rr] = (o2 < K2) ? b2[obase + o2] : 0.f;
            }
        // C/D layout: col = lane&15 -> x = nt*16+lm, row = lg*4+rr (+16 mt) -> o2
        #pragma unroll
        for (int nt = 0; nt < 4; ++nt)
            #pragma unroll
            for (int mt = 0; mt < 4; ++mt)
                #pragma unroll
                for (int rr = 0; rr < 4; ++rr) {
                    const int o2 = mt * 16 + lg * 4 + rr;
                    if (o2 < K2)
                        wg[gi][o2][nt * 16 + lm] = acc[nt][mt][rr] + bias[mt][rr];
                }
    }
    __syncthreads();

    // ---------------- Phase C: 4 channels x 4 px per thread ----------------
    const int gi  = tid >> 6;             // wave-uniform
    const int clq = (tid >> 4) & 3;
    const int xq  = tid & 15;
    const int x0  = xq * 4;
    const int c0  = (gq * 4 + gi) * GCH + clq * 4;
    const float* fb = feat + ((size_t)bb * CC + c0) * HW;

    float s[4][4];                        // [ch][px]
    #pragma unroll
    for (int cc = 0; cc < 4; ++cc) {
        const float4 r = *reinterpret_cast<const float4*>(fb + (size_t)cc * HW + (size_t)y * WW + x0);
        s[cc][0] = r.x; s[cc][1] = r.y; s[cc][2] = r.z; s[cc][3] = r.w;   // residual
    }

    #pragma unroll
    for (int i = 0; i < 7; ++i) {
        const int yy = y + i - 3;
        if (yy < 0 || yy >= HH) continue;          // block-uniform branch
        float buf[4][12];
        #pragma unroll
        for (int cc = 0; cc < 4; ++cc) {
            const float* fr = fb + (size_t)cc * HW + (size_t)yy * WW;
            float4 L = make_float4(0.f, 0.f, 0.f, 0.f);
            float4 Rr = L;
            const float4 M = *reinterpret_cast<const float4*>(fr + x0);
            if (xq > 0)  L  = *reinterpret_cast<const float4*>(fr + x0 - 4);
            if (xq < 15) Rr = *reinterpret_cast<const float4*>(fr + x0 + 4);
            buf[cc][0] = L.x;  buf[cc][1] = L.y;  buf[cc][2]  = L.z;  buf[cc][3]  = L.w;
            buf[cc][4] = M.x;  buf[cc][5] = M.y;  buf[cc][6]  = M.z;  buf[cc][7]  = M.w;
            buf[cc][8] = Rr.x; buf[cc][9] = Rr.y; buf[cc][10] = Rr.z; buf[cc][11] = Rr.w;
        }
        #pragma unroll
        for (int jx = 0; jx < 7; ++jx) {
            const float4 w4 = *reinterpret_cast<const float4*>(&wg[gi][i * 7 + jx][x0]);
            #pragma unroll
            for (int cc = 0; cc < 4; ++cc) {
                s[cc][0] = fmaf(w4.x, buf[cc][jx + 1], s[cc][0]);
                s[cc][1] = fmaf(w4.y, buf[cc][jx + 2], s[cc][1]);
                s[cc][2] = fmaf(w4.z, buf[cc][jx + 3], s[cc][2]);
                s[cc][3] = fmaf(w4.w, buf[cc][jx + 4], s[cc][3]);
            }
        }
    }

    float* ob = out + ((size_t)bb * CC + c0) * HW + (size_t)y * WW + x0;
    #pragma unroll
    for (int cc = 0; cc < 4; ++cc) {
        float4 o4; o4.x = s[cc][0]; o4.y = s[cc][1]; o4.z = s[cc][2]; o4.w = s[cc][3];
        *reinterpret_cast<float4*>(ob + (size_t)cc * HW) = o4;
    }
}

// ================= Fallback: fused single kernel (used only if ws too small) =================
__global__ __launch_bounds__(512, 1) void crossinv_fused_kernel(
    const float* __restrict__ feat, const float* __restrict__ guide,
    const float* __restrict__ w1, const float* __restrict__ gamma,
    const float* __restrict__ beta, const float* __restrict__ mean,
    const float* __restrict__ var, const float* __restrict__ w2,
    const float* __restrict__ b2, float* __restrict__ out)
{
    __shared__ float stf[RED][WW];
    __shared__ float wgf[K2][WW];
    const int bid  = blockIdx.x;
    const int bb   = bid >> 7;
    const int y    = (bid >> 1) & 63;
    const int gsel = bid & 1;
    const int lane = threadIdx.x & 63;
    const int wv   = __builtin_amdgcn_readfirstlane(threadIdx.x >> 6);

    const float* gptr = guide + (size_t)bb * CC * HW + (size_t)y * WW + lane;
    float acc[8];
    #pragma unroll
    for (int j = 0; j < 8; ++j) acc[j] = 0.f;
    for (int c0 = 0; c0 < CC; c0 += 4) {
        const float gv0 = gptr[(c0 + 0) * HW];
        const float gv1 = gptr[(c0 + 1) * HW];
        const float gv2 = gptr[(c0 + 2) * HW];
        const float gv3 = gptr[(c0 + 3) * HW];
        #pragma unroll
        for (int j = 0; j < 8; ++j) {
            const int o = wv + 8 * j;
            const float4 wr = *reinterpret_cast<const float4*>(w1 + o * CC + c0);
            acc[j] = fmaf(wr.x, gv0, acc[j]);
            acc[j] = fmaf(wr.y, gv1, acc[j]);
            acc[j] = fmaf(wr.z, gv2, acc[j]);
            acc[j] = fmaf(wr.w, gv3, acc[j]);
        }
    }
    #pragma unroll
    for (int j = 0; j < 8; ++j) {
        const int o = wv + 8 * j;
        const float sc = gamma[o] * rsqrtf(var[o] + 1e-5f);
        const float sh = beta[o] - mean[o] * sc;
        const float v  = fmaf(acc[j], sc, sh);
        stf[o][lane] = v > 0.f ? v : 0.f;
    }
    __syncthreads();
    for (int gi = 0; gi < 8; ++gi) {
        const int gg    = gsel * 8 + gi;
        const int obase = gg * K2;
        float accw[7];
        #pragma unroll
        for (int j = 0; j < 7; ++j) {
            const int o2 = wv + 8 * j;
            accw[j] = (o2 < K2) ? b2[obase + o2] : 0.f;
        }
        for (int r0 = 0; r0 < RED; r0 += 4) {
            const float t0 = stf[r0 + 0][lane];
            const float t1 = stf[r0 + 1][lane];
            const float t2 = stf[r0 + 2][lane];
            const float t3 = stf[r0 + 3][lane];
            #pragma unroll
            for (int j = 0; j < 7; ++j) {
                const int o2 = wv + 8 * j;
                if (o2 < K2) {
                    const float4 wr = *reinterpret_cast<const float4*>(
                        w2 + (size_t)(obase + o2) * RED + r0);
                    accw[j] = fmaf(wr.x, t0, accw[j]);
                    accw[j] = fmaf(wr.y, t1, accw[j]);
                    accw[j] = fmaf(wr.z, t2, accw[j]);
                    accw[j] = fmaf(wr.w, t3, accw[j]);
                }
            }
        }
        #pragma unroll
        for (int j = 0; j < 7; ++j) {
            const int o2 = wv + 8 * j;
            if (o2 < K2) wgf[o2][lane] = accw[j];
        }
        __syncthreads();
        #pragma unroll
        for (int cc2 = 0; cc2 < 2; ++cc2) {
            const int cc = wv * 2 + cc2;
            const int cch = gg * GCH + cc;
            const float* fbp = feat + ((size_t)bb * CC + cch) * HW;
            float sum = fbp[y * WW + lane];
            #pragma unroll
            for (int i = 0; i < 7; ++i) {
                const int yy = y + i - 3;
                if (yy < 0 || yy >= HH) continue;
                const float* frow = fbp + yy * WW;
                #pragma unroll
                for (int jx = 0; jx < 7; ++jx) {
                    const int xx = lane + jx - 3;
                    const float fv = (xx >= 0 && xx < WW) ? frow[xx] : 0.f;
                    sum = fmaf(wgf[i * 7 + jx][lane], fv, sum);
                }
            }
            out[((size_t)bb * CC + cch) * HW + (size_t)y * WW + lane] = sum;
        }
        __syncthreads();
    }
}

extern "C" void kernel_launch(void* const* d_in, const int* in_sizes, int n_in,
                              void* d_out, int out_size, void* d_ws, size_t ws_size,
                              hipStream_t stream) {
    const float* feat  = (const float*)d_in[0];
    const float* guide = (const float*)d_in[1];
    const float* w1    = (const float*)d_in[2];
    const float* gamma = (const float*)d_in[3];
    const float* beta  = (const float*)d_in[4];
    const float* mean  = (const float*)d_in[5];
    const float* var   = (const float*)d_in[6];
    const float* w2    = (const float*)d_in[7];
    const float* b2    = (const float*)d_in[8];
    float* out = (float*)d_out;

    if (ws_size >= (size_t)WS_NEED) {
        unsigned short* wsu = (unsigned short*)d_ws;
        float* scsh = (float*)((char*)d_ws + SCSH_BYTE);
        hipLaunchKernelGGL(k0_prep, dim3(35), dim3(256), 0, stream,
                           w1, w2, gamma, beta, mean, var, wsu, scsh);
        hipLaunchKernelGGL(fused_kernel, dim3(512), dim3(256), 0, stream,
                           feat, guide, wsu, scsh, b2, out);
    } else {
        hipLaunchKernelGGL(crossinv_fused_kernel, dim3(256), dim3(512), 0, stream,
                           feat, guide, w1, gamma, beta, mean, var, w2, b2, out);
    }
}